// Round 9
// baseline (233.263 us; speedup 1.0000x reference)
//
#include <hip/hip_runtime.h>

// VQ quantizer, fp32: z [131072,64], e [2048,64].
// d_out (flat f32): z_q [131072*64] | indices [131072] (floats) | loss [1].
//
// 2-split bf16 MFMA scan (hh, hl, lh products), argmax of s = dot - esq/2.
// Round 6/8 post-mortem: the register allocator refuses to keep A-fragments
// resident (VGPR 84-88, VALU-busy 81us vs ~20us static, identical with and
// without asm pins) -> restructure: the wave's z-tile (bf16 hi/lo) lives in
// wave-private LDS and fragments are ds_read_b128 from LDS inside the loop.
// LDS pipe co-issues with MFMA (m114), so the rebuild cost is bounded by
// construction. Row stride 144 B = 9x16 -> 2-way bank aliasing only (free).
// Top-2 gap < EPS_S flags rows for exact f64 re-solve (coalesced eT).
// T=0 => z_out = z_q = e[best].

#define N_ROWS 131072
#define ZD 64
#define KCODES 2048
#define EPS_S 2e-3f
#define FLAG_CAP 32768

using bf16x8  = __attribute__((ext_vector_type(8))) short;
using floatx4 = __attribute__((ext_vector_type(4))) float;

__device__ inline float bf2f(unsigned short u) {
    union { unsigned int i; float f; } c; c.i = ((unsigned int)u) << 16; return c.f;
}
__device__ inline unsigned short f2bf(float x) {
    union { float f; unsigned int i; } c; c.f = x;
    unsigned int b = c.i + 0x7FFFu + ((c.i >> 16) & 1u);
    return (unsigned short)(b >> 16);
}

// ws byte layout:
//       0: loss f32 | 4: flag count u32
//    4096: esn f32[2048]   (= -esq/2, summed in f64)
//   16384: esq64 f64[2048]
//   32768: ehi u16[2048*64] | 294912: elo u16[2048*64]
//  557056: eT f32[64*2048]
// 1081344: flags u32[32768]   (ends 1212416)

__global__ void prep_kernel(const float* __restrict__ e, float* __restrict__ ws) {
    int t = threadIdx.x, lane = t & 63, w = t >> 6;
    if (blockIdx.x == 0 && t == 0) { ws[0] = 0.0f; ((unsigned int*)ws)[1] = 0u; }
    int c = blockIdx.x * 4 + w;                   // 512 blocks x 4 waves = 2048
    float* esn = ws + 1024;
    double* esq64 = (double*)((char*)ws + 16384);
    unsigned short* ehi = (unsigned short*)((char*)ws + 32768);
    unsigned short* elo = (unsigned short*)((char*)ws + 294912);
    float* eT = (float*)((char*)ws + 557056);

    float x = e[(size_t)c * ZD + lane];           // lane = dim k, coalesced
    unsigned short h = f2bf(x);
    ehi[c * ZD + lane] = h;
    elo[c * ZD + lane] = f2bf(x - bf2f(h));
    eT[lane * KCODES + c] = x;
    double s = (double)x * (double)x;
    for (int off = 1; off < 64; off <<= 1) s += __shfl_xor(s, off, 64);
    if (lane == 0) { esq64[c] = s; esn[c] = (float)(-0.5 * s); }
}

__global__ __launch_bounds__(128, 2) void vq_mfma(
        const float* __restrict__ z, const float* __restrict__ e,
        float* __restrict__ ws, float* __restrict__ out) {
    const float* esn = ws + 1024;
    const unsigned short* ehi = (const unsigned short*)((const char*)ws + 32768);
    const unsigned short* elo = (const unsigned short*)((const char*)ws + 294912);
    unsigned int* cntp  = (unsigned int*)ws + 1;
    unsigned int* flags = (unsigned int*)((char*)ws + 1081344);

    int lane = threadIdx.x & 63;
    int w    = threadIdx.x >> 6;                  // 0..1 (2 waves/block)
    int wid  = blockIdx.x * 2 + w;                // 0..2047
    int row0 = wid * 64;                          // 64 rows per wave
    int lrow = lane & 15;
    int lq   = lane >> 4;

    // Wave-private z-tile in LDS: hi/lo planes, row stride 72 shorts (144 B).
    __shared__ __align__(16) short zs[2][2][64][72];
    for (int r = 0; r < 64; r++) {
        float x = z[(size_t)(row0 + r) * ZD + lane];   // coalesced 256 B/row
        unsigned short hb = f2bf(x);
        zs[w][0][r][lane] = (short)hb;
        zs[w][1][r][lane] = (short)f2bf(x - bf2f(hb));
    }
    // No barrier: each wave reads only its own region; within-wave DS
    // ordering is handled by lgkmcnt.

    // argmax state on s = dot - esq/2  (argmin d2 == argmax s)
    floatx4 mval[4], mv2[4], midx[4];
#pragma unroll
    for (int rf = 0; rf < 4; rf++)
#pragma unroll
        for (int r = 0; r < 4; r++) {
            mval[rf][r] = -3.0e38f; mv2[rf][r] = -3.0e38f; midx[rf][r] = 0.0f;
        }

    const unsigned short* bhp = ehi + lrow * ZD + lq * 8;
    const unsigned short* blp = elo + lrow * ZD + lq * 8;
    bf16x8 h0 = *(const bf16x8*)(const void*)(bhp);
    bf16x8 h1 = *(const bf16x8*)(const void*)(bhp + 32);
    bf16x8 l0 = *(const bf16x8*)(const void*)(blp);
    bf16x8 l1 = *(const bf16x8*)(const void*)(blp + 32);
    float  en = esn[lrow];

    const short* Zh = &zs[w][0][0][0];
    const short* Zl = &zs[w][1][0][0];

    for (int ct = 0; ct < 128; ct++) {
        // prefetch next B tile (wraps on last iter; harmless)
        int nn = ((ct + 1) & 127) * 16;
        int noff = nn * ZD;
        bf16x8 nh0 = *(const bf16x8*)(const void*)(bhp + noff);
        bf16x8 nh1 = *(const bf16x8*)(const void*)(bhp + noff + 32);
        bf16x8 nl0 = *(const bf16x8*)(const void*)(blp + noff);
        bf16x8 nl1 = *(const bf16x8*)(const void*)(blp + noff + 32);
        float  nen = esn[nn + lrow];

        float fcol = (float)(ct * 16 + lrow);
#pragma unroll
        for (int rf = 0; rf < 4; rf++) {
            int ab = (rf * 16 + lrow) * 72 + lq * 8;
            bf16x8 ah0 = *(const bf16x8*)(const void*)(Zh + ab);
            bf16x8 ah1 = *(const bf16x8*)(const void*)(Zh + ab + 32);
            bf16x8 al0 = *(const bf16x8*)(const void*)(Zl + ab);
            bf16x8 al1 = *(const bf16x8*)(const void*)(Zl + ab + 32);
            floatx4 acc = {en, en, en, en};       // start at -esq/2
            acc = __builtin_amdgcn_mfma_f32_16x16x32_bf16(ah0, h0, acc, 0, 0, 0);
            acc = __builtin_amdgcn_mfma_f32_16x16x32_bf16(ah1, h1, acc, 0, 0, 0);
            acc = __builtin_amdgcn_mfma_f32_16x16x32_bf16(ah0, l0, acc, 0, 0, 0);
            acc = __builtin_amdgcn_mfma_f32_16x16x32_bf16(ah1, l1, acc, 0, 0, 0);
            acc = __builtin_amdgcn_mfma_f32_16x16x32_bf16(al0, h0, acc, 0, 0, 0);
            acc = __builtin_amdgcn_mfma_f32_16x16x32_bf16(al1, h1, acc, 0, 0, 0);
#pragma unroll
            for (int r = 0; r < 4; r++) {
                float s  = acc[r];
                bool  gt = s > mval[rf][r];
                mv2[rf][r]  = fmaxf(fminf(s, mval[rf][r]), mv2[rf][r]);
                midx[rf][r] = gt ? fcol : midx[rf][r];
                mval[rf][r] = fmaxf(s, mval[rf][r]);
            }
        }
        h0 = nh0; h1 = nh1; l0 = nl0; l1 = nl1; en = nen;
    }

    float lacc = 0.0f;
#pragma unroll
    for (int rf = 0; rf < 4; rf++)
#pragma unroll
        for (int r = 0; r < 4; r++) {
            float v = mval[rf][r], v2 = mv2[rf][r], fi = midx[rf][r];
            // top-2 max-merge across the 16 lanes of this row (ties: smaller col)
            for (int off = 1; off < 16; off <<= 1) {
                float ov  = __shfl_xor(v,  off, 64);
                float ofi = __shfl_xor(fi, off, 64);
                float ov2 = __shfl_xor(v2, off, 64);
                bool take = (ov > v) || ((ov == v) && (ofi < fi));
                float loser = take ? v : ov;
                v2 = fmaxf(fmaxf(v2, ov2), loser);
                v  = take ? ov  : v;
                fi = take ? ofi : fi;
            }
            int row = row0 + rf * 16 + lq * 4 + r;
            int idx = (int)fi;
            float4 ev = ((const float4*)(const void*)(e + (size_t)idx * ZD))[lrow];
            float4 zv = ((const float4*)(const void*)(z + (size_t)row * ZD))[lrow];
            ((float4*)(void*)(out + (size_t)row * ZD))[lrow] = ev;
            float dx = ev.x - zv.x, dy = ev.y - zv.y;
            float dz = ev.z - zv.z, dw = ev.w - zv.w;
            lacc = fmaf(dx, dx, lacc); lacc = fmaf(dy, dy, lacc);
            lacc = fmaf(dz, dz, lacc); lacc = fmaf(dw, dw, lacc);
            if (lrow == 0) {
                out[(size_t)N_ROWS * ZD + row] = fi;
                if (v - v2 < EPS_S) {
                    unsigned int i = atomicAdd(cntp, 1u);
                    if (i < FLAG_CAP) flags[i] = (unsigned int)row;
                }
            }
        }

    for (int off = 1; off < 64; off <<= 1) lacc += __shfl_xor(lacc, off, 64);
    __shared__ float sm[2];
    if (lane == 0) sm[w] = lacc;
    __syncthreads();
    if (threadIdx.x == 0) atomicAdd(ws, sm[0] + sm[1]);
}

__global__ __launch_bounds__(256) void vq_fixup(
        const float* __restrict__ z, const float* __restrict__ e,
        float* __restrict__ ws, float* __restrict__ out) {
    const double* esq64 = (const double*)((const char*)ws + 16384);
    const float* eT = (const float*)((const char*)ws + 557056);
    const unsigned int* flags = (const unsigned int*)((const char*)ws + 1081344);
    unsigned int cnt = ((const unsigned int*)ws)[1];
    if (cnt > FLAG_CAP) cnt = FLAG_CAP;

    // finalize loss (ws[0] is complete once vq_mfma finished)
    if (blockIdx.x == 0 && threadIdx.x == 0)
        out[(size_t)N_ROWS * ZD + N_ROWS] = ws[0] * (1.0f / 8388608.0f);

    __shared__ float zrow[ZD];
    __shared__ double sd[4]; __shared__ int si[4]; __shared__ int sbest;
    int t = threadIdx.x, lane = t & 63, w = t >> 6;

    for (unsigned int u = blockIdx.x; u < cnt; u += gridDim.x) {
        int row = (int)flags[u];
        __syncthreads();                          // protect zrow from prev iter
        if (t < ZD) zrow[t] = z[(size_t)row * ZD + t];
        __syncthreads();

        double dacc[8];
#pragma unroll
        for (int j = 0; j < 8; j++) dacc[j] = 0.0;
        for (int k = 0; k < ZD; k++) {
            double zk = (double)zrow[k];
            const float* ek = eT + k * KCODES + t;
#pragma unroll
            for (int j = 0; j < 8; j++)
                dacc[j] = fma(zk, (double)ek[256 * j], dacc[j]);
        }
        double dmin = 1.0e300; int imin = 0;
#pragma unroll
        for (int j = 0; j < 8; j++) {             // ascending c: first wins
            int c = t + 256 * j;
            double d = fma(-2.0, dacc[j], esq64[c]);
            if (d < dmin) { dmin = d; imin = c; }
        }
        for (int off = 1; off < 64; off <<= 1) {
            double od = __shfl_xor(dmin, off, 64);
            int    oi = __shfl_xor(imin, off, 64);
            if (od < dmin || (od == dmin && oi < imin)) { dmin = od; imin = oi; }
        }
        if (lane == 0) { sd[w] = dmin; si[w] = imin; }
        __syncthreads();
        if (t == 0) {
            double bd = sd[0]; int bi = si[0];
            for (int q = 1; q < 4; q++)
                if (sd[q] < bd || (sd[q] == bd && si[q] < bi)) { bd = sd[q]; bi = si[q]; }
            sbest = bi;
        }
        __syncthreads();
        int bi = sbest;
        if (t < 16)
            ((float4*)(void*)(out + (size_t)row * ZD))[t] =
                ((const float4*)(const void*)(e + (size_t)bi * ZD))[t];
        if (t == 0) out[(size_t)N_ROWS * ZD + row] = (float)bi;
        // loss correction from flips: < EPS * ~1e3 / 8.4M < 3e-7 — ignored.
    }
}

extern "C" void kernel_launch(void* const* d_in, const int* in_sizes, int n_in,
                              void* d_out, int out_size, void* d_ws, size_t ws_size,
                              hipStream_t stream) {
    const float* z = (const float*)d_in[0];
    const float* e = (const float*)d_in[1];
    float* out = (float*)d_out;
    float* ws  = (float*)d_ws;

    prep_kernel<<<dim3(512), dim3(256), 0, stream>>>(e, ws);
    vq_mfma<<<dim3(1024), dim3(128), 0, stream>>>(z, e, ws, out);
    vq_fixup<<<dim3(256), dim3(256), 0, stream>>>(z, e, ws, out);
}